// Round 5
// baseline (82.907 us; speedup 1.0000x reference)
//
#include <hip/hip_runtime.h>
#include <math.h>

#define IN_CH 4
#define KSZ 3
#define NUM_KERNELS 2
#define NPOS 9          // KSZ*KSZ
#define HH 64
#define WW 64
#define BB 16
#define OH 62
#define OW 62
#define NPATCH (BB*OH*OW)   // 61504 = 961 * 64 exactly
#define NU (NPOS*IN_CH)     // 36 unitaries per kernel index
#define UFLOATS (NU*8)      // 288 floats
#define BLK 64

// One thread per (patch, kernel-index). 16 complex amplitudes in registers
// (qubit q <-> amplitude bit 8>>q). The 9-position loop is ROLLED
// (#pragma unroll 1): fully unrolling gave a ~44 KB instruction stream that
// overflows the 32 KB per-CU I-cache (R4 theory for the 4x gap vs issue
// bound). Rolled body ~5.6 KB stays I$-resident; CX becomes explicit
// register swaps (compiler nets them into moves), x loads happen per-pos.
__global__ __launch_bounds__(BLK) void qk_main(const float* __restrict__ x,
                                               const float* __restrict__ w,
                                               float* __restrict__ out) {
    __shared__ float sU[UFLOATS];
    const int kidx = blockIdx.y;
    const int tid  = threadIdx.x;

    // ---- in-block precompute: lane t<36 builds fused U = Rz*Ry*Rx for (pos,q)=t
    if (tid < NU) {
        const float* wp = w + kidx * (NU * 3) + tid * 3;  // w.reshape(NPOS,1,IN_CH,3)
        float hx = 0.5f * wp[0], hy = 0.5f * wp[1], hz = 0.5f * wp[2];
        float cx = cosf(hx), sx = sinf(hx);
        float cy = cosf(hy), sy = sinf(hy);
        float cz = cosf(hz), sz = sinf(hz);
        // M = Ry * Rx
        float m00r =  cy * cx, m00i =  sy * sx;
        float m01r = -sy * cx, m01i = -cy * sx;
        float m10r =  sy * cx, m10i = -cy * sx;
        float m11r =  cy * cx, m11i = -sy * sx;
        // U = Rz * M
        float* o = &sU[tid * 8];
        o[0] = cz * m00r + sz * m00i;  o[1] = cz * m00i - sz * m00r;
        o[2] = cz * m01r + sz * m01i;  o[3] = cz * m01i - sz * m01r;
        o[4] = cz * m10r - sz * m10i;  o[5] = cz * m10i + sz * m10r;
        o[6] = cz * m11r - sz * m11i;  o[7] = cz * m11i + sz * m11r;
    }
    __syncthreads();   // 1 wave/wg: compiles to a waitcnt, ~free

    const int p   = blockIdx.x * BLK + tid;   // NPATCH == 961*64: no tail guard
    const int b   = p / (OH * OW);
    const int rem = p - b * (OH * OW);
    const int oh  = rem / OW;
    const int ow  = rem - oh * OW;
    const float* xp = x + b * (IN_CH * HH * WW) + oh * WW + ow;

    float sr[16], si[16];
    #pragma unroll
    for (int i = 0; i < 16; ++i) { sr[i] = 0.25f; si[i] = 0.0f; }  // H^⊗4 |0>

    int ubase = 0;
    #pragma unroll 1
    for (int kh = 0; kh < KSZ; ++kh) {
        #pragma unroll 1
        for (int kw = 0; kw < KSZ; ++kw) {
            const float* xq = xp + kh * WW + kw;
            // ---- fused per-qubit gate F = U_w(pos,q) * RY(x_angle) ----
            #pragma unroll
            for (int q = 0; q < IN_CH; ++q) {
                float s, c;
                __sincosf(0.5f * xq[q * (HH * WW)], &s, &c);
                const float* u = &sU[ubase + q * 8];
                const float u00r = u[0], u00i = u[1], u01r = u[2], u01i = u[3];
                const float u10r = u[4], u10i = u[5], u11r = u[6], u11i = u[7];
                // F[:,0] = c*U[:,0] + s*U[:,1] ; F[:,1] = c*U[:,1] - s*U[:,0]
                const float f00r = c * u00r + s * u01r, f00i = c * u00i + s * u01i;
                const float f10r = c * u10r + s * u11r, f10i = c * u10i + s * u11i;
                const float f01r = c * u01r - s * u00r, f01i = c * u01i - s * u00i;
                const float f11r = c * u11r - s * u10r, f11i = c * u11i - s * u10i;
                const int mask = 8 >> q;
                #pragma unroll
                for (int i = 0; i < 16; ++i) {
                    if (i & mask) continue;
                    const int j = i | mask;
                    float ar = sr[i], ai = si[i], br = sr[j], bi = si[j];
                    sr[i] = f00r * ar - f00i * ai + f01r * br - f01i * bi;
                    si[i] = f00r * ai + f00i * ar + f01r * bi + f01i * br;
                    sr[j] = f10r * ar - f10i * ai + f11r * br - f11i * bi;
                    si[j] = f10r * ai + f10i * ar + f11r * bi + f11i * br;
                }
            }
            // ---- CX ring (0→1),(1→2),(2→3),(3→0): explicit swaps; the
            // compiler copy-propagates these into a net move set per iter ----
            #pragma unroll
            for (int e = 0; e < 4; ++e) {
                const int cmask = 8 >> e;
                const int tmask = 8 >> ((e + 1) & 3);
                #pragma unroll
                for (int i = 0; i < 16; ++i) {
                    if ((i & cmask) && !(i & tmask)) {
                        const int j = i | tmask;
                        float tr = sr[i]; sr[i] = sr[j]; sr[j] = tr;
                        float ti = si[i]; si[i] = si[j]; si[j] = ti;
                    }
                }
            }
            ubase += 32;
        }
    }

    // ---- probabilities and <Z_q> ----
    float p2[16];
    #pragma unroll
    for (int i = 0; i < 16; ++i) p2[i] = sr[i] * sr[i] + si[i] * si[i];

    float* ob = out + ((size_t)(b * (NUM_KERNELS * IN_CH) + kidx * IN_CH) * OH + oh) * OW + ow;
    #pragma unroll
    for (int q = 0; q < IN_CH; ++q) {
        const int mask = 8 >> q;
        float e = 0.0f;
        #pragma unroll
        for (int i = 0; i < 16; ++i) e += (i & mask) ? -p2[i] : p2[i];
        ob[q * (OH * OW)] = e;
    }
}

extern "C" void kernel_launch(void* const* d_in, const int* in_sizes, int n_in,
                              void* d_out, int out_size, void* d_ws, size_t ws_size,
                              hipStream_t stream) {
    const float* x = (const float*)d_in[0];
    const float* w = (const float*)d_in[1];
    float* out = (float*)d_out;
    (void)d_ws; (void)ws_size;

    dim3 grid(NPATCH / BLK, NUM_KERNELS);   // 961 x 2, one wave per workgroup
    hipLaunchKernelGGL(qk_main, grid, dim3(BLK), 0, stream, x, w, out);
}

// Round 6
// 81.560 us; speedup vs baseline: 1.0165x; 1.0165x over previous
//
#include <hip/hip_runtime.h>
#include <math.h>

#define IN_CH 4
#define KSZ 3
#define NUM_KERNELS 2
#define NPOS 9          // KSZ*KSZ
#define HH 64
#define WW 64
#define BB 16
#define OH 62
#define OW 62
#define NPATCH (BB*OH*OW)   // 61504 = 961 * 64 exactly
#define NU (NPOS*IN_CH)     // 36 unitaries per kernel index
#define UFLOATS (NU*8)      // 288 floats
#define BLK 64
#define CHST (HH*WW)        // channel plane stride

// ---------------------------------------------------------------------------
// Precompute fused U = Rz*Ry*Rx per (kernel,pos,qubit). 72 threads.
// (Identical to the R3/R4-verified version.)
// ---------------------------------------------------------------------------
__global__ void qk_precompute(const float* __restrict__ w, float* __restrict__ U) {
    int t = blockIdx.x * blockDim.x + threadIdx.x;
    if (t >= NUM_KERNELS * NU) return;
    int k   = t / NU;
    int rem = t % NU;          // pos*IN_CH + q
    const float* wp = w + k * (NU * 3) + rem * 3;
    float hx = 0.5f * wp[0], hy = 0.5f * wp[1], hz = 0.5f * wp[2];
    float cx = cosf(hx), sx = sinf(hx);
    float cy = cosf(hy), sy = sinf(hy);
    float cz = cosf(hz), sz = sinf(hz);
    float m00r =  cy * cx, m00i =  sy * sx;
    float m01r = -sy * cx, m01i = -cy * sx;
    float m10r =  sy * cx, m10i = -cy * sx;
    float m11r =  cy * cx, m11i = -sy * sx;
    float* o = U + t * 8;
    o[0] = cz * m00r + sz * m00i;  o[1] = cz * m00i - sz * m00r;
    o[2] = cz * m01r + sz * m01i;  o[3] = cz * m01i - sz * m01r;
    o[4] = cz * m10r - sz * m10i;  o[5] = cz * m10i + sz * m10r;
    o[6] = cz * m11r - sz * m11i;  o[7] = cz * m11i + sz * m11r;
}

// ---------------------------------------------------------------------------
// Main kernel. One thread per (patch,kidx); 16 complex amps in registers.
// Outer loop ROLLED over the 3 kernel rows (t3 = kh); inner 3 positions fully
// unrolled -> ~16 KB body that stays L1I-resident across iterations (R4's
// fully-unrolled ~44 KB stream thrashed the 32 KB I$: ~2k stall cyc/gate).
// CX relabeling is free inside the triple; x values for row t3+1 are
// prefetched while row t3 computes (no exposed vmcnt, unlike R5).
// ---------------------------------------------------------------------------
__global__ __launch_bounds__(BLK) void qk_main(const float* __restrict__ x,
                                               const float* __restrict__ Uglob,
                                               float* __restrict__ out) {
    __shared__ float sU[UFLOATS];
    const int kidx = blockIdx.y;
    const int tid  = threadIdx.x;
    for (int t = tid; t < UFLOATS; t += BLK) sU[t] = Uglob[kidx * UFLOATS + t];
    __syncthreads();

    const int p   = blockIdx.x * BLK + tid;   // no tail: 961*64 == NPATCH
    const int b   = p / (OH * OW);
    const int rem = p - b * (OH * OW);
    const int oh  = rem / OW;
    const int ow  = rem - oh * OW;
    const float* xp = x + b * (IN_CH * CHST) + oh * WW + ow;

    float sr[16], si[16];
    #pragma unroll
    for (int i = 0; i < 16; ++i) { sr[i] = 0.25f; si[i] = 0.0f; }  // H^⊗4|0>

    // current-row / next-row x values (static indexing only)
    float xc[12], xn[12];
    #pragma unroll
    for (int ch = 0; ch < IN_CH; ++ch)
        #pragma unroll
        for (int u = 0; u < 3; ++u)
            xc[ch * 3 + u] = xp[ch * CHST + u];

    #pragma unroll 1
    for (int t3 = 0; t3 < 3; ++t3) {          // t3 == kh (row of the window)
        if (t3 < 2) {                          // prefetch next row (uniform branch)
            #pragma unroll
            for (int ch = 0; ch < IN_CH; ++ch)
                #pragma unroll
                for (int u = 0; u < 3; ++u)
                    xn[ch * 3 + u] = xp[ch * CHST + (t3 + 1) * WW + u];
        }
        const int ub3 = t3 * 96;               // LDS float offset of this row's U's
        #pragma unroll
        for (int u = 0; u < 3; ++u) {          // kw within the row
            // ---- fused gate F = U_w(pos,q) * RY(x) per qubit ----
            #pragma unroll
            for (int q = 0; q < IN_CH; ++q) {
                float s, c;
                __sincosf(0.5f * xc[q * 3 + u], &s, &c);
                const float* uu = &sU[ub3 + u * 32 + q * 8];
                const float u00r = uu[0], u00i = uu[1], u01r = uu[2], u01i = uu[3];
                const float u10r = uu[4], u10i = uu[5], u11r = uu[6], u11i = uu[7];
                const float f00r = c * u00r + s * u01r, f00i = c * u00i + s * u01i;
                const float f10r = c * u10r + s * u11r, f10i = c * u10i + s * u11i;
                const float f01r = c * u01r - s * u00r, f01i = c * u01i - s * u00i;
                const float f11r = c * u11r - s * u10r, f11i = c * u11i - s * u10i;
                const int mask = 8 >> q;
                #pragma unroll
                for (int i = 0; i < 16; ++i) {
                    if (i & mask) continue;
                    const int j = i | mask;
                    float ar = sr[i], ai = si[i], br = sr[j], bi = si[j];
                    sr[i] = f00r * ar - f00i * ai + f01r * br - f01i * bi;
                    si[i] = f00r * ai + f00i * ar + f01r * bi + f01i * br;
                    sr[j] = f10r * ar - f10i * ai + f11r * br - f11i * bi;
                    si[j] = f10r * ai + f10i * ar + f11r * bi + f11i * br;
                }
            }
            // ---- CX ring: free relabel inside the unrolled triple; movs
            //      only at the rolled t3 boundary (3 instead of 9) ----
            #pragma unroll
            for (int e = 0; e < 4; ++e) {
                const int cmask = 8 >> e;
                const int tmask = 8 >> ((e + 1) & 3);
                #pragma unroll
                for (int i = 0; i < 16; ++i) {
                    if ((i & cmask) && !(i & tmask)) {
                        const int j = i | tmask;
                        float tr = sr[i]; sr[i] = sr[j]; sr[j] = tr;
                        float ti = si[i]; si[i] = si[j]; si[j] = ti;
                    }
                }
            }
        }
        #pragma unroll
        for (int i = 0; i < 12; ++i) xc[i] = xn[i];
    }

    // ---- probabilities and <Z_q> ----
    float p2[16];
    #pragma unroll
    for (int i = 0; i < 16; ++i) p2[i] = sr[i] * sr[i] + si[i] * si[i];

    float* ob = out + ((size_t)(b * (NUM_KERNELS * IN_CH) + kidx * IN_CH) * OH + oh) * OW + ow;
    #pragma unroll
    for (int q = 0; q < IN_CH; ++q) {
        const int mask = 8 >> q;
        float e = 0.0f;
        #pragma unroll
        for (int i = 0; i < 16; ++i) e += (i & mask) ? -p2[i] : p2[i];
        ob[q * (OH * OW)] = e;
    }
}

extern "C" void kernel_launch(void* const* d_in, const int* in_sizes, int n_in,
                              void* d_out, int out_size, void* d_ws, size_t ws_size,
                              hipStream_t stream) {
    const float* x = (const float*)d_in[0];
    const float* w = (const float*)d_in[1];
    float* out = (float*)d_out;
    float* U   = (float*)d_ws;   // 2*288 floats

    hipLaunchKernelGGL(qk_precompute, dim3(1), dim3(128), 0, stream, w, U);
    dim3 grid(NPATCH / BLK, NUM_KERNELS);   // 961 x 2, one wave per wg
    hipLaunchKernelGGL(qk_main, grid, dim3(BLK), 0, stream, x, U, out);
}

// Round 7
// 78.804 us; speedup vs baseline: 1.0521x; 1.0350x over previous
//
#include <hip/hip_runtime.h>
#include <math.h>

#define IN_CH 4
#define KSZ 3
#define NUM_KERNELS 2
#define NPOS 9          // KSZ*KSZ
#define HH 64
#define WW 64
#define BB 16
#define OH 62
#define OW 62
#define NPATCH (BB*OH*OW)   // 61504 = 961 * 64 exactly
#define NU (NPOS*IN_CH)     // 36 gates per kernel index
#define CHST (HH*WW)
#define BLK 64
// SU(2) storage: per (kidx,pos,q) only alpha,beta (U = [[a,b],[-b*,a*]])
#define UF4 (NUM_KERNELS*NU*4)   // 288 floats

// ---------------------------------------------------------------------------
// Precompute alpha=U00, beta=U01 of U = Rz*Ry*Rx per (kernel,pos,qubit).
// (First half of the R3-verified 8-float version; U10=-conj(U01),
//  U11=conj(U00) verified algebraically from the same formulas.)
// ---------------------------------------------------------------------------
__global__ void qk_precompute(const float* __restrict__ w, float* __restrict__ U) {
    int t = blockIdx.x * blockDim.x + threadIdx.x;
    if (t >= NUM_KERNELS * NU) return;
    int k   = t / NU;
    int rem = t % NU;          // pos*IN_CH + q
    const float* wp = w + k * (NU * 3) + rem * 3;
    float hx = 0.5f * wp[0], hy = 0.5f * wp[1], hz = 0.5f * wp[2];
    float cx = cosf(hx), sx = sinf(hx);
    float cy = cosf(hy), sy = sinf(hy);
    float cz = cosf(hz), sz = sinf(hz);
    float m00r =  cy * cx, m00i =  sy * sx;     // (Ry*Rx)[0][0]
    float m01r = -sy * cx, m01i = -cy * sx;     // (Ry*Rx)[0][1]
    float* o = U + t * 4;
    o[0] = cz * m00r + sz * m00i;  o[1] = cz * m00i - sz * m00r;  // alpha
    o[2] = cz * m01r + sz * m01i;  o[3] = cz * m01i - sz * m01r;  // beta
}

// Apply SU(2) gate F=[[fa,fb],[-fb*,fa*]] to pairs (i, i|mask). All indices
// compile-time after inlining in unrolled context -> registers only.
__device__ __forceinline__ void gate2(float sr[16], float si[16], const int mask,
                                      const float far_, const float fai,
                                      const float fbr, const float fbi) {
    #pragma unroll
    for (int i = 0; i < 16; ++i) {
        if (i & mask) continue;
        const int j = i | mask;
        float ar = sr[i], ai = si[i], br = sr[j], bi = si[j];
        sr[i] =  far_ * ar - fai * ai + fbr * br - fbi * bi;
        si[i] =  far_ * ai + fai * ar + fbr * bi + fbi * br;
        sr[j] = -fbr * ar - fbi * ai + far_ * br + fai * bi;
        si[j] =  fbi * ar - fbr * ai - fai * br + far_ * bi;
    }
}

__device__ __forceinline__ void cx_ring(float sr[16], float si[16]) {
    #pragma unroll
    for (int e = 0; e < 4; ++e) {
        const int cmask = 8 >> e;
        const int tmask = 8 >> ((e + 1) & 3);
        #pragma unroll
        for (int i = 0; i < 16; ++i) {
            if ((i & cmask) && !(i & tmask)) {
                const int j = i | tmask;
                float tr = sr[i]; sr[i] = sr[j]; sr[j] = tr;
                float ti = si[i]; si[i] = si[j]; si[j] = ti;
            }
        }
    }
}

// ---------------------------------------------------------------------------
// Main kernel: ONE thread per patch, BOTH kernel-indices' circuits in that
// thread (two independent 16-amp states -> 2x independent FMA streams per
// wave, attacking the R6 finding: VALUBusy 36% at ~1.3 waves/SIMD =
// dependency-latency starvation). Shared angles: trig/loads amortized over
// both circuits. Fully unrolled (R4's fastest structure).
// ---------------------------------------------------------------------------
__global__ __launch_bounds__(BLK) void qk_main(const float* __restrict__ x,
                                               const float* __restrict__ Uglob,
                                               float* __restrict__ out) {
    __shared__ float sU[UF4];
    const int tid = threadIdx.x;
    for (int t = tid; t < UF4; t += BLK) sU[t] = Uglob[t];
    __syncthreads();

    const int p   = blockIdx.x * BLK + tid;   // no tail: 961*64 == NPATCH
    const int b   = p / (OH * OW);
    const int rem = p - b * (OH * OW);
    const int oh  = rem / OW;
    const int ow  = rem - oh * OW;
    const float* xp = x + b * (IN_CH * CHST) + oh * WW + ow;

    float s0r[16], s0i[16], s1r[16], s1i[16];
    #pragma unroll
    for (int i = 0; i < 16; ++i) {
        s0r[i] = 0.25f; s0i[i] = 0.0f;   // H^⊗4 |0>
        s1r[i] = 0.25f; s1i[i] = 0.0f;
    }

    #pragma unroll
    for (int kh = 0; kh < KSZ; ++kh) {
        #pragma unroll
        for (int kw = 0; kw < KSZ; ++kw) {
            const int pos = kh * KSZ + kw;
            #pragma unroll
            for (int q = 0; q < IN_CH; ++q) {
                const float th = xp[q * CHST + kh * WW + kw];
                float s, c;
                __sincosf(0.5f * th, &s, &c);       // shared by both circuits
                const int mask = 8 >> q;
                // kidx 0
                {
                    const float* u = &sU[(pos * IN_CH + q) * 4];
                    const float far_ = c * u[0] + s * u[2], fai = c * u[1] + s * u[3];
                    const float fbr  = c * u[2] - s * u[0], fbi = c * u[3] - s * u[1];
                    gate2(s0r, s0i, mask, far_, fai, fbr, fbi);
                }
                // kidx 1
                {
                    const float* u = &sU[(NU + pos * IN_CH + q) * 4];
                    const float far_ = c * u[0] + s * u[2], fai = c * u[1] + s * u[3];
                    const float fbr  = c * u[2] - s * u[0], fbi = c * u[3] - s * u[1];
                    gate2(s1r, s1i, mask, far_, fai, fbr, fbi);
                }
            }
            cx_ring(s0r, s0i);   // register renames (unrolled context)
            cx_ring(s1r, s1i);
        }
    }

    // ---- probabilities and <Z_q> for both circuits ----
    float p20[16], p21[16];
    #pragma unroll
    for (int i = 0; i < 16; ++i) {
        p20[i] = s0r[i] * s0r[i] + s0i[i] * s0i[i];
        p21[i] = s1r[i] * s1r[i] + s1i[i] * s1i[i];
    }

    float* ob = out + ((size_t)(b * (NUM_KERNELS * IN_CH)) * OH + oh) * OW + ow;
    #pragma unroll
    for (int q = 0; q < IN_CH; ++q) {
        const int mask = 8 >> q;
        float e0 = 0.0f, e1 = 0.0f;
        #pragma unroll
        for (int i = 0; i < 16; ++i) {
            e0 += (i & mask) ? -p20[i] : p20[i];
            e1 += (i & mask) ? -p21[i] : p21[i];
        }
        ob[(size_t)q * (OH * OW)]            = e0;   // channel q        (kidx 0)
        ob[(size_t)(IN_CH + q) * (OH * OW)]  = e1;   // channel 4+q      (kidx 1)
    }
}

extern "C" void kernel_launch(void* const* d_in, const int* in_sizes, int n_in,
                              void* d_out, int out_size, void* d_ws, size_t ws_size,
                              hipStream_t stream) {
    const float* x = (const float*)d_in[0];
    const float* w = (const float*)d_in[1];
    float* out = (float*)d_out;
    float* U   = (float*)d_ws;   // 288 floats of scratch

    hipLaunchKernelGGL(qk_precompute, dim3(1), dim3(128), 0, stream, w, U);
    hipLaunchKernelGGL(qk_main, dim3(NPATCH / BLK), dim3(BLK), 0, stream, x, U, out);
}